// Round 17
// baseline (124.997 us; speedup 1.0000x reference)
//
#include <hip/hip_runtime.h>
#include <hip/hip_bf16.h>

// Problem constants
#define BDIM 8
#define HDIM 64
#define WDIM 64
#define CDIM 192
#define CIDIM 384
#define MTOK (BDIM * HDIM * WDIM)   // 32768 tokens

using bf16 = __hip_bfloat16;
typedef __attribute__((ext_vector_type(8))) short short8;   // 8 bf16 (4 VGPRs)
typedef __attribute__((ext_vector_type(4))) float f32x4;

__device__ __forceinline__ float silu_f(float v) { return v / (1.0f + __expf(-v)); }
__device__ __forceinline__ float bf2f(short s) {
    union { unsigned u; float f; } x; x.u = ((unsigned)(unsigned short)s) << 16; return x.f;
}

__device__ __forceinline__ void gload_lds16(const bf16* g, bf16* l) {
    __builtin_amdgcn_global_load_lds(
        (const __attribute__((address_space(1))) void*)g,
        (__attribute__((address_space(3))) void*)l, 16, 0, 0);
}

#define MFMA16(a, b, c) __builtin_amdgcn_mfma_f32_16x16x32_bf16(a, b, c, 0, 0, 0)

// ---------------------------------------------------------------------------
// PERSISTENT K=192 GEMM (G1) with counted-vmcnt async prefetch.
// EPI 0: split c<384 -> outB (x1, stride 384); else outB2 = 4*silu(v)
// ---------------------------------------------------------------------------
#define NSTRIPE 40
template <int EPI>
__launch_bounds__(256, 2)
__global__ void gemm_k192_p(const bf16* __restrict__ A, const bf16* __restrict__ BT,
                            const float* __restrict__ bias,
                            bf16* __restrict__ outB, bf16* __restrict__ outB2)
{
    __shared__ bf16 As[2][64 * 192];
    __shared__ bf16 Bs[64 * 192];

    const int bid = blockIdx.x;
    const int n   = bid / NSTRIPE;
    const int s   = bid % NSTRIPE;
    const int n0  = n * 64;

    const int tid  = threadIdx.x;
    const int lane = tid & 63;
    const int wv   = tid >> 6;
    const int wm   = wv >> 1;
    const int wn   = wv & 1;

    int soff[6];
    #pragma unroll
    for (int i = 0; i < 6; ++i) {
        const int ci   = wv * 6 + i;
        const int c    = ci * 64 + lane;
        const int row  = c / 24;
        const int slot = c - row * 24;
        soff[i] = row * 192 + (slot ^ (row & 7)) * 8;
    }

    #pragma unroll
    for (int i = 0; i < 6; ++i)
        gload_lds16(BT + (size_t)n0 * 192 + soff[i], &Bs[(wv * 6 + i) * 512]);
    #pragma unroll
    for (int i = 0; i < 6; ++i)
        gload_lds16(A + (size_t)(s * 64) * 192 + soff[i], &As[0][(wv * 6 + i) * 512]);

    const int mloc[2] = { wm * 32 + (lane & 15), wm * 32 + 16 + (lane & 15) };
    const int nloc[2] = { wn * 32 + (lane & 15), wn * 32 + 16 + (lane & 15) };
    const bool isZ = (EPI == 0) && (n0 >= CIDIM);
    bf16* dst        = (EPI == 0) ? (isZ ? outB2 : outB) : outB;
    const int stride = (EPI == 0) ? CIDIM : 768;
    const int col0   = (EPI == 0) ? (isZ ? n0 - CIDIM : n0) : n0;

    int cur = 0;
    for (int mt = s; mt < 512; mt += NSTRIPE) {
        const int nmt = mt + NSTRIPE;
        if (nmt < 512) {
            const bf16* a1 = A + (size_t)(nmt * 64) * 192;
            bf16* db = As[cur ^ 1];
            #pragma unroll
            for (int i = 0; i < 6; ++i)
                gload_lds16(a1 + soff[i], &db[(wv * 6 + i) * 512]);
            asm volatile("s_waitcnt vmcnt(6)" ::: "memory");
        } else {
            asm volatile("s_waitcnt vmcnt(0)" ::: "memory");
        }
        __builtin_amdgcn_sched_barrier(0);
        __builtin_amdgcn_s_barrier();
        __builtin_amdgcn_sched_barrier(0);

        const bf16* la = As[cur];
        f32x4 acc[2][2] = {};
        __builtin_amdgcn_s_setprio(1);
        #pragma unroll
        for (int ks = 0; ks < 6; ++ks) {
            const int t = ks * 4 + (lane >> 4);
            short8 af[2], bfr[2];
            #pragma unroll
            for (int mi = 0; mi < 2; ++mi) {
                const int m = mloc[mi];
                af[mi] = *reinterpret_cast<const short8*>(&la[m * 192 + ((t ^ (m & 7)) << 3)]);
            }
            #pragma unroll
            for (int ni = 0; ni < 2; ++ni) {
                const int nn = nloc[ni];
                bfr[ni] = *reinterpret_cast<const short8*>(&Bs[nn * 192 + ((t ^ (nn & 7)) << 3)]);
            }
            #pragma unroll
            for (int mi = 0; mi < 2; ++mi)
                #pragma unroll
                for (int ni = 0; ni < 2; ++ni)
                    acc[mi][ni] = MFMA16(af[mi], bfr[ni], acc[mi][ni]);
        }
        __builtin_amdgcn_s_setprio(0);

        __builtin_amdgcn_sched_barrier(0);
        __builtin_amdgcn_s_barrier();
        __builtin_amdgcn_sched_barrier(0);

        const int m0   = mt * 64;
        const int rowb = m0 + wm * 32 + (lane >> 4) * 4;
        const int colb = col0 + wn * 32 + (lane & 15);
        #pragma unroll
        for (int mi = 0; mi < 2; ++mi) {
            #pragma unroll
            for (int ni = 0; ni < 2; ++ni) {
                const int c = colb + ni * 16;
                #pragma unroll
                for (int j = 0; j < 4; ++j) {
                    const int row = rowb + mi * 16 + j;
                    float v = acc[mi][ni][j];
                    if constexpr (EPI == 0) {
                        if (isZ) v = 4.0f * silu_f(v);
                    } else {
                        v = silu_f(v + bias[n0 + (c - col0)]);
                    }
                    dst[(size_t)row * stride + c] = __float2bfloat16(v);
                }
            }
        }
        cur ^= 1;
    }
}

// ---------------------------------------------------------------------------
// G3 loop GEMM (K=384): out = bf16(xb + y@Wout). BM=128, BN=64, BK=64.
// ---------------------------------------------------------------------------
__launch_bounds__(256, 4)
__global__ void gemm_g3(const bf16* __restrict__ A, const bf16* __restrict__ BT,
                        const bf16* __restrict__ residB, bf16* __restrict__ outB,
                        int M, int N, int K, int NX)
{
    __shared__ bf16 As[128 * 64];
    __shared__ bf16 Bs[64 * 64];

    const int bid = blockIdx.x;
    const int c8  = bid & 7;
    const int kq  = bid >> 3;
    const int bx  = kq % NX;
    const int by  = (kq / NX) * 8 + c8;
    const int m0  = by * 128;
    const int n0  = bx * 64;

    const int tid  = threadIdx.x;
    const int lane = tid & 63;
    const int wv   = tid >> 6;
    const int wm   = wv >> 1;
    const int wn   = wv & 1;

    const int srow  = lane >> 3;
    const int sslot = lane & 7;

    f32x4 acc[4][2] = {};

    for (int k0 = 0; k0 < K; k0 += 64) {
        #pragma unroll
        for (int i = 0; i < 4; ++i) {
            const int rb = wv * 32 + i * 8;
            const int r  = rb + srow;
            gload_lds16(A + (size_t)(m0 + r) * K + k0 + ((sslot ^ (r & 7)) << 3),
                        &As[rb * 64]);
        }
        #pragma unroll
        for (int i = 0; i < 2; ++i) {
            const int rb = wv * 16 + i * 8;
            const int r  = rb + srow;
            gload_lds16(BT + (size_t)(n0 + r) * K + k0 + ((sslot ^ (r & 7)) << 3),
                        &Bs[rb * 64]);
        }
        __syncthreads();

        #pragma unroll
        for (int kk = 0; kk < 2; ++kk) {
            const int t = kk * 4 + (lane >> 4);
            short8 af[4], bfr[2];
            #pragma unroll
            for (int mi = 0; mi < 4; ++mi) {
                const int m = wm * 64 + mi * 16 + (lane & 15);
                af[mi] = *reinterpret_cast<const short8*>(&As[m * 64 + ((t ^ (m & 7)) << 3)]);
            }
            #pragma unroll
            for (int ni = 0; ni < 2; ++ni) {
                const int n = wn * 32 + ni * 16 + (lane & 15);
                bfr[ni] = *reinterpret_cast<const short8*>(&Bs[n * 64 + ((t ^ (n & 7)) << 3)]);
            }
            #pragma unroll
            for (int mi = 0; mi < 4; ++mi)
                #pragma unroll
                for (int ni = 0; ni < 2; ++ni)
                    acc[mi][ni] = MFMA16(af[mi], bfr[ni], acc[mi][ni]);
        }
        __syncthreads();
    }

    const int colb = n0 + wn * 32 + (lane & 15);
    const int rowb = m0 + wm * 64 + (lane >> 4) * 4;
    #pragma unroll
    for (int mi = 0; mi < 4; ++mi) {
        #pragma unroll
        for (int ni = 0; ni < 2; ++ni) {
            const int c = colb + ni * 16;
            #pragma unroll
            for (int j = 0; j < 4; ++j) {
                const int row = rowb + mi * 16 + j;
                const size_t off = (size_t)row * N + c;
                outB[off] = __float2bfloat16(acc[mi][ni][j] +
                                             bf2f(*(const short*)&residB[off]));
            }
        }
    }
}

// ---------------------------------------------------------------------------
// FUSED MLP (G4+G5), 32-row tiles, K-CHUNKED (3 rounds of 256 h-cols):
// final = ob + silu(ob@Wm1+bm1)@Wm2 + bm2.
// LDS: obs 12KB + hs[32 x 264] 16.5KB = 28.7KB -> 4-5 blocks/CU.
// Round r3: ph1 computes h cols [r3*256,(r3+1)*256) (wave = 4 n-frags) -> hs;
// barrier; ph2 accumulates ks = r3*8..+8 into persistent facc; barrier.
// Weights fragment-ordered (Wm1F 48frag x 6ks, Wm2F 12frag x 24ks): each
// B-frag load = contiguous 1KB wave-line from L2.
// ---------------------------------------------------------------------------
#define HST2 264
__launch_bounds__(256, 4)
__global__ void fused_mlp_kc(const bf16* __restrict__ ob, const bf16* __restrict__ Wm1F,
                             const bf16* __restrict__ Wm2F, const float* __restrict__ bm1,
                             const float* __restrict__ bm2, float* __restrict__ out)
{
    __shared__ bf16 obs[32 * 192];     // 12 KB
    __shared__ bf16 hs[32 * HST2];     // 16.5 KB

    const int m0   = blockIdx.x * 32;
    const int tid  = threadIdx.x;
    const int lane = tid & 63;
    const int wv   = tid >> 6;
    const int l15  = lane & 15;
    const int l4   = lane >> 4;

    // stage obs (768 16B chunks; k192 slot swizzle p^(row&7))
    #pragma unroll
    for (int i = 0; i < 3; ++i) {
        const int ci   = wv * 3 + i;
        const int c    = ci * 64 + lane;
        const int row  = c / 24;
        const int slot = c - row * 24;
        gload_lds16(ob + (size_t)(m0 + row) * 192 + ((slot ^ (row & 7)) << 3),
                    &obs[ci * 512]);
    }
    __syncthreads();

    f32x4 facc[2][3] = {};

    for (int r3 = 0; r3 < 3; ++r3) {
        // ---- phase 1: h cols [r3*256, r3*256+256); wave owns 4 n-frags ----
        f32x4 hacc[2][4] = {};
        #pragma unroll
        for (int ks = 0; ks < 6; ++ks) {
            short8 af[2];
            #pragma unroll
            for (int mi = 0; mi < 2; ++mi) {
                const int r = mi * 16 + l15;
                af[mi] = *reinterpret_cast<const short8*>(
                    &obs[r * 192 + (((ks * 4 + l4) ^ (r & 7)) << 3)]);
            }
            #pragma unroll
            for (int ni = 0; ni < 4; ++ni) {
                const int f1 = r3 * 16 + wv * 4 + ni;       // global n-frag 0..47
                const short8 b = *reinterpret_cast<const short8*>(
                    Wm1F + ((size_t)(f1 * 6 + ks) * 64 + lane) * 8);
                #pragma unroll
                for (int mi = 0; mi < 2; ++mi)
                    hacc[mi][ni] = MFMA16(af[mi], b, hacc[mi][ni]);
            }
        }
        #pragma unroll
        for (int ni = 0; ni < 4; ++ni) {
            const int gcol = (r3 * 16 + wv * 4 + ni) * 16 + l15;   // global col
            const int lc   = (wv * 4 + ni) * 16 + l15;             // col in round
            const float bb = bm1[gcol];
            #pragma unroll
            for (int mi = 0; mi < 2; ++mi)
                #pragma unroll
                for (int j = 0; j < 4; ++j) {
                    const int r = mi * 16 + l4 * 4 + j;
                    hs[r * HST2 + lc] = __float2bfloat16(silu_f(hacc[mi][ni][j] + bb));
                }
        }
        __syncthreads();

        // ---- phase 2: accumulate 8 global ks = r3*8+kk into facc ----
        #pragma unroll
        for (int kk = 0; kk < 8; ++kk) {
            short8 ha[2];
            #pragma unroll
            for (int mi = 0; mi < 2; ++mi) {
                const int r = mi * 16 + l15;
                ha[mi] = *reinterpret_cast<const short8*>(&hs[r * HST2 + kk * 32 + l4 * 8]);
            }
            #pragma unroll
            for (int ni = 0; ni < 3; ++ni) {
                const int f2  = wv * 3 + ni;                 // out n-frag 0..11
                const int gks = r3 * 8 + kk;
                const short8 b = *reinterpret_cast<const short8*>(
                    Wm2F + ((size_t)(f2 * 24 + gks) * 64 + lane) * 8);
                #pragma unroll
                for (int mi = 0; mi < 2; ++mi)
                    facc[mi][ni] = MFMA16(ha[mi], b, facc[mi][ni]);
            }
        }
        __syncthreads();   // hs free for next round
    }

    // epilogue: + bm2 + bf16 ob residual (from obs), fp32 out
    #pragma unroll
    for (int ni = 0; ni < 3; ++ni) {
        const int col = (wv * 3 + ni) * 16 + l15;
        const float b2 = bm2[col];
        #pragma unroll
        for (int mi = 0; mi < 2; ++mi)
            #pragma unroll
            for (int j = 0; j < 4; ++j) {
                const int r  = mi * 16 + l4 * 4 + j;
                const int ch = (col >> 3) ^ (r & 7);
                const float resid = bf2f(*reinterpret_cast<const short*>(
                    &obs[r * 192 + ch * 8 + (col & 7)]));
                out[(size_t)(m0 + r) * 192 + col] = facc[mi][ni][j] + b2 + resid;
            }
    }
}

// ---------------------------------------------------------------------------
// Depthwise 3x3 conv + bias + silu, gated (dense streams).
// ---------------------------------------------------------------------------
__launch_bounds__(256)
__global__ void dwconv_gate_v6(const bf16* __restrict__ x1, const bf16* __restrict__ sz,
                               const float* __restrict__ wT, const float* __restrict__ conv_b,
                               bf16* __restrict__ y)
{
    const int bid = blockIdx.x;
    const int swz = (bid & 7) * ((int)gridDim.x >> 3) + (bid >> 3);
    const int f   = swz * 256 + threadIdx.x;
    const int m   = f / 48;
    const int cg  = f - m * 48;
    const int c0  = cg * 8;
    const int h   = (m >> 6) & 63;
    const int w   = m & 63;

    float acc[8];
    {
        const f32x4 ba = *reinterpret_cast<const f32x4*>(&conv_b[c0]);
        const f32x4 bb = *reinterpret_cast<const f32x4*>(&conv_b[c0 + 4]);
        acc[0] = ba[0]; acc[1] = ba[1]; acc[2] = ba[2]; acc[3] = ba[3];
        acc[4] = bb[0]; acc[5] = bb[1]; acc[6] = bb[2]; acc[7] = bb[3];
    }

    #pragma unroll
    for (int r = 0; r < 3; ++r) {
        const int hh = h + r - 1;
        if (hh < 0 || hh >= HDIM) continue;
        #pragma unroll
        for (int dw = 0; dw < 3; ++dw) {
            const int ww = w + dw - 1;
            if (ww < 0 || ww >= WDIM) continue;
            const int mm  = m + (r - 1) * WDIM + (dw - 1);
            const int tap = r * 3 + dw;
            const short8 t = *reinterpret_cast<const short8*>(&x1[(size_t)mm * CIDIM + c0]);
            const f32x4 wa = *reinterpret_cast<const f32x4*>(&wT[tap * CIDIM + c0]);
            const f32x4 wb = *reinterpret_cast<const f32x4*>(&wT[tap * CIDIM + c0 + 4]);
            acc[0] += bf2f(t[0]) * wa[0]; acc[1] += bf2f(t[1]) * wa[1];
            acc[2] += bf2f(t[2]) * wa[2]; acc[3] += bf2f(t[3]) * wa[3];
            acc[4] += bf2f(t[4]) * wb[0]; acc[5] += bf2f(t[5]) * wb[1];
            acc[6] += bf2f(t[6]) * wb[2]; acc[7] += bf2f(t[7]) * wb[3];
        }
    }

    const short8 g = *reinterpret_cast<const short8*>(&sz[(size_t)m * CIDIM + c0]);
    bf16 tmp[8];
    #pragma unroll
    for (int j = 0; j < 8; ++j)
        tmp[j] = __float2bfloat16(silu_f(acc[j]) * bf2f(g[j]));
    *reinterpret_cast<short8*>(&y[(size_t)m * CIDIM + c0]) =
        *reinterpret_cast<const short8*>(tmp);
}

// ---------------------------------------------------------------------------
// ALL preprocessing in ONE launch: x->bf16, WinT/WoutT transposes,
// Wm1F/Wm2F FRAGMENT-ORDER layouts, conv_w transpose.
// ---------------------------------------------------------------------------
#define SZ_WIN  (192 * 768)
#define SZ_WOUT (384 * 192)
#define SZ_WM1  (192 * 768)
#define SZ_WM2  (768 * 192)
#define SZ_CW   (CIDIM * 9)
#define XCVT    (MTOK * CDIM / 4)
#define SZ_ALL  (XCVT + SZ_WIN + SZ_WOUT + SZ_WM1 + SZ_WM2 + SZ_CW)

__launch_bounds__(256)
__global__ void prep_all(const float* __restrict__ x, const float* __restrict__ Win,
                         const float* __restrict__ Wout, const float* __restrict__ Wm1,
                         const float* __restrict__ Wm2, const float* __restrict__ convw,
                         bf16* __restrict__ xb, bf16* __restrict__ WinT,
                         bf16* __restrict__ WoutT, bf16* __restrict__ Wm1F,
                         bf16* __restrict__ Wm2F, float* __restrict__ wTc)
{
    int idx = blockIdx.x * 256 + threadIdx.x;
    if (idx < XCVT) {
        const int i = idx * 4;
        const float4 v = *reinterpret_cast<const float4*>(&x[i]);
        xb[i + 0] = __float2bfloat16(v.x);
        xb[i + 1] = __float2bfloat16(v.y);
        xb[i + 2] = __float2bfloat16(v.z);
        xb[i + 3] = __float2bfloat16(v.w);
        return;
    }
    idx -= XCVT;
    if (idx < SZ_WIN) {
        const int r = idx / 768, c = idx % 768;
        WinT[(size_t)c * 192 + r] = __float2bfloat16(Win[idx]);
        return;
    }
    idx -= SZ_WIN;
    if (idx < SZ_WOUT) {
        const int r = idx / 192, c = idx % 192;
        WoutT[(size_t)c * 384 + r] = __float2bfloat16(Wout[idx]);
        return;
    }
    idx -= SZ_WOUT;
    if (idx < SZ_WM1) {
        // fragment order: [f:48][ks:6][lane:64][e:8]; row=f*16+(l&15), k=ks*32+(l>>4)*8+e
        const int f  = idx / 3072;
        const int r1 = idx - f * 3072;
        const int ks = r1 / 512;
        const int r2 = r1 - ks * 512;
        const int l  = r2 >> 3;
        const int e  = r2 & 7;
        const int row = f * 16 + (l & 15);
        const int k   = ks * 32 + (l >> 4) * 8 + e;
        Wm1F[idx] = __float2bfloat16(Wm1[(size_t)k * 768 + row]);
        return;
    }
    idx -= SZ_WM1;
    if (idx < SZ_WM2) {
        // fragment order: [f:12][ks:24][lane:64][e:8]; row=f*16+(l&15), k=ks*32+(l>>4)*8+e
        const int f  = idx / 12288;
        const int r1 = idx - f * 12288;
        const int ks = r1 / 512;
        const int r2 = r1 - ks * 512;
        const int l  = r2 >> 3;
        const int e  = r2 & 7;
        const int row = f * 16 + (l & 15);
        const int k   = ks * 32 + (l >> 4) * 8 + e;
        Wm2F[idx] = __float2bfloat16(Wm2[(size_t)k * 192 + row]);
        return;
    }
    idx -= SZ_WM2;
    if (idx < SZ_CW) {
        const int ci = idx / 9, t = idx % 9;
        wTc[t * CIDIM + ci] = convw[idx];
    }
}

// ---------------------------------------------------------------------------
extern "C" void kernel_launch(void* const* d_in, const int* in_sizes, int n_in,
                              void* d_out, int out_size, void* d_ws, size_t ws_size,
                              hipStream_t stream)
{
    const float* x      = (const float*)d_in[0];
    const float* Win    = (const float*)d_in[1];
    const float* conv_w = (const float*)d_in[2];
    const float* conv_b = (const float*)d_in[3];
    const float* Wout   = (const float*)d_in[4];
    const float* Wm1    = (const float*)d_in[5];
    const float* bm1    = (const float*)d_in[6];
    const float* Wm2    = (const float*)d_in[7];
    const float* bm2    = (const float*)d_in[8];
    float* out = (float*)d_out;

    char* ws = (char*)d_ws;
    size_t o = 0;
    bf16*  xb    = (bf16*)(ws + o); o += (size_t)MTOK * CDIM * 2;
    bf16*  WinT  = (bf16*)(ws + o); o += (size_t)768 * 192 * 2;
    bf16*  WoutT = (bf16*)(ws + o); o += (size_t)192 * 384 * 2;
    bf16*  Wm1F  = (bf16*)(ws + o); o += (size_t)SZ_WM1 * 2;
    bf16*  Wm2F  = (bf16*)(ws + o); o += (size_t)SZ_WM2 * 2;
    float* wTc   = (float*)(ws + o); o += (size_t)9 * CIDIM * 4;
    bf16*  ws_x1 = (bf16*)(ws + o); o += (size_t)MTOK * CIDIM * 2;   // dense x1 [M,384]
    bf16*  ws_sz = (bf16*)(ws + o); o += (size_t)MTOK * CIDIM * 2;   // dense 4*silu(z)
    bf16*  ws_y  = (bf16*)(ws + o); o += (size_t)MTOK * CIDIM * 2;
    bf16*  ws_ob = (bf16*)(ws + o); o += (size_t)MTOK * CDIM * 2;    // out bf16 [M,192]

    // 0) all conversions / re-layouts in one launch
    prep_all<<<dim3((SZ_ALL + 255) / 256), dim3(256), 0, stream>>>(
        x, Win, Wout, Wm1, Wm2, conv_w, xb, WinT, WoutT, Wm1F, Wm2F, wTc);

    // 1) xz = x @ Win  [M,768], K=192 -> split dense x1 / sz(=4*silu(z))
    gemm_k192_p<0><<<dim3(12 * NSTRIPE), dim3(256), 0, stream>>>(
        xb, WinT, nullptr, ws_x1, ws_sz);

    // 2) y = silu(dwconv(x1)+b) * sz -> bf16
    dwconv_gate_v6<<<dim3(MTOK * 48 / 256), dim3(256), 0, stream>>>(
        ws_x1, ws_sz, wTc, conv_b, ws_y);

    // 3) out = xb + y @ Wout   [M,192], K=384 -> bf16 ob
    gemm_g3<<<dim3(3 * 256), dim3(256), 0, stream>>>(
        ws_y, WoutT, xb, ws_ob, MTOK, CDIM, CIDIM, 3);

    // 4+5) final = ob + silu(ob@Wm1+bm1)@Wm2 + bm2 -> fp32 out (FUSED, K-chunked)
    fused_mlp_kc<<<dim3(MTOK / 32), dim3(256), 0, stream>>>(
        ws_ob, Wm1F, Wm2F, bm1, bm2, out);
}

// Round 18
// 117.133 us; speedup vs baseline: 1.0671x; 1.0671x over previous
//
#include <hip/hip_runtime.h>
#include <hip/hip_bf16.h>

// Problem constants
#define BDIM 8
#define HDIM 64
#define WDIM 64
#define CDIM 192
#define CIDIM 384
#define MTOK (BDIM * HDIM * WDIM)   // 32768 tokens

using bf16 = __hip_bfloat16;
typedef __attribute__((ext_vector_type(8))) short short8;   // 8 bf16 (4 VGPRs)
typedef __attribute__((ext_vector_type(4))) float f32x4;

__device__ __forceinline__ float silu_f(float v) { return v / (1.0f + __expf(-v)); }
__device__ __forceinline__ float bf2f(short s) {
    union { unsigned u; float f; } x; x.u = ((unsigned)(unsigned short)s) << 16; return x.f;
}

__device__ __forceinline__ void gload_lds16(const bf16* g, bf16* l) {
    __builtin_amdgcn_global_load_lds(
        (const __attribute__((address_space(1))) void*)g,
        (__attribute__((address_space(3))) void*)l, 16, 0, 0);
}

#define MFMA16(a, b, c) __builtin_amdgcn_mfma_f32_16x16x32_bf16(a, b, c, 0, 0, 0)

// ---------------------------------------------------------------------------
// PERSISTENT K=192 GEMM (G1) with counted-vmcnt async prefetch.
// EPI 0: split c<384 -> outB (x1, stride 384); else outB2 = 4*silu(v)
// ---------------------------------------------------------------------------
#define NSTRIPE 40
template <int EPI>
__launch_bounds__(256, 2)
__global__ void gemm_k192_p(const bf16* __restrict__ A, const bf16* __restrict__ BT,
                            const float* __restrict__ bias,
                            bf16* __restrict__ outB, bf16* __restrict__ outB2)
{
    __shared__ bf16 As[2][64 * 192];
    __shared__ bf16 Bs[64 * 192];

    const int bid = blockIdx.x;
    const int n   = bid / NSTRIPE;
    const int s   = bid % NSTRIPE;
    const int n0  = n * 64;

    const int tid  = threadIdx.x;
    const int lane = tid & 63;
    const int wv   = tid >> 6;
    const int wm   = wv >> 1;
    const int wn   = wv & 1;

    int soff[6];
    #pragma unroll
    for (int i = 0; i < 6; ++i) {
        const int ci   = wv * 6 + i;
        const int c    = ci * 64 + lane;
        const int row  = c / 24;
        const int slot = c - row * 24;
        soff[i] = row * 192 + (slot ^ (row & 7)) * 8;
    }

    #pragma unroll
    for (int i = 0; i < 6; ++i)
        gload_lds16(BT + (size_t)n0 * 192 + soff[i], &Bs[(wv * 6 + i) * 512]);
    #pragma unroll
    for (int i = 0; i < 6; ++i)
        gload_lds16(A + (size_t)(s * 64) * 192 + soff[i], &As[0][(wv * 6 + i) * 512]);

    const int mloc[2] = { wm * 32 + (lane & 15), wm * 32 + 16 + (lane & 15) };
    const int nloc[2] = { wn * 32 + (lane & 15), wn * 32 + 16 + (lane & 15) };
    const bool isZ = (EPI == 0) && (n0 >= CIDIM);
    bf16* dst        = (EPI == 0) ? (isZ ? outB2 : outB) : outB;
    const int stride = (EPI == 0) ? CIDIM : 768;
    const int col0   = (EPI == 0) ? (isZ ? n0 - CIDIM : n0) : n0;

    int cur = 0;
    for (int mt = s; mt < 512; mt += NSTRIPE) {
        const int nmt = mt + NSTRIPE;
        if (nmt < 512) {
            const bf16* a1 = A + (size_t)(nmt * 64) * 192;
            bf16* db = As[cur ^ 1];
            #pragma unroll
            for (int i = 0; i < 6; ++i)
                gload_lds16(a1 + soff[i], &db[(wv * 6 + i) * 512]);
            asm volatile("s_waitcnt vmcnt(6)" ::: "memory");
        } else {
            asm volatile("s_waitcnt vmcnt(0)" ::: "memory");
        }
        __builtin_amdgcn_sched_barrier(0);
        __builtin_amdgcn_s_barrier();
        __builtin_amdgcn_sched_barrier(0);

        const bf16* la = As[cur];
        f32x4 acc[2][2] = {};
        __builtin_amdgcn_s_setprio(1);
        #pragma unroll
        for (int ks = 0; ks < 6; ++ks) {
            const int t = ks * 4 + (lane >> 4);
            short8 af[2], bfr[2];
            #pragma unroll
            for (int mi = 0; mi < 2; ++mi) {
                const int m = mloc[mi];
                af[mi] = *reinterpret_cast<const short8*>(&la[m * 192 + ((t ^ (m & 7)) << 3)]);
            }
            #pragma unroll
            for (int ni = 0; ni < 2; ++ni) {
                const int nn = nloc[ni];
                bfr[ni] = *reinterpret_cast<const short8*>(&Bs[nn * 192 + ((t ^ (nn & 7)) << 3)]);
            }
            #pragma unroll
            for (int mi = 0; mi < 2; ++mi)
                #pragma unroll
                for (int ni = 0; ni < 2; ++ni)
                    acc[mi][ni] = MFMA16(af[mi], bfr[ni], acc[mi][ni]);
        }
        __builtin_amdgcn_s_setprio(0);

        __builtin_amdgcn_sched_barrier(0);
        __builtin_amdgcn_s_barrier();
        __builtin_amdgcn_sched_barrier(0);

        const int m0   = mt * 64;
        const int rowb = m0 + wm * 32 + (lane >> 4) * 4;
        const int colb = col0 + wn * 32 + (lane & 15);
        #pragma unroll
        for (int mi = 0; mi < 2; ++mi) {
            #pragma unroll
            for (int ni = 0; ni < 2; ++ni) {
                const int c = colb + ni * 16;
                #pragma unroll
                for (int j = 0; j < 4; ++j) {
                    const int row = rowb + mi * 16 + j;
                    float v = acc[mi][ni][j];
                    if constexpr (EPI == 0) {
                        if (isZ) v = 4.0f * silu_f(v);
                    } else {
                        v = silu_f(v + bias[n0 + (c - col0)]);
                    }
                    dst[(size_t)row * stride + c] = __float2bfloat16(v);
                }
            }
        }
        cur ^= 1;
    }
}

// ---------------------------------------------------------------------------
// G3 loop GEMM (K=384): out = bf16(xb + y@Wout). BM=128, BN=64, BK=64.
// ---------------------------------------------------------------------------
__launch_bounds__(256, 4)
__global__ void gemm_g3(const bf16* __restrict__ A, const bf16* __restrict__ BT,
                        const bf16* __restrict__ residB, bf16* __restrict__ outB,
                        int M, int N, int K, int NX)
{
    __shared__ bf16 As[128 * 64];
    __shared__ bf16 Bs[64 * 64];

    const int bid = blockIdx.x;
    const int c8  = bid & 7;
    const int kq  = bid >> 3;
    const int bx  = kq % NX;
    const int by  = (kq / NX) * 8 + c8;
    const int m0  = by * 128;
    const int n0  = bx * 64;

    const int tid  = threadIdx.x;
    const int lane = tid & 63;
    const int wv   = tid >> 6;
    const int wm   = wv >> 1;
    const int wn   = wv & 1;

    const int srow  = lane >> 3;
    const int sslot = lane & 7;

    f32x4 acc[4][2] = {};

    for (int k0 = 0; k0 < K; k0 += 64) {
        #pragma unroll
        for (int i = 0; i < 4; ++i) {
            const int rb = wv * 32 + i * 8;
            const int r  = rb + srow;
            gload_lds16(A + (size_t)(m0 + r) * K + k0 + ((sslot ^ (r & 7)) << 3),
                        &As[rb * 64]);
        }
        #pragma unroll
        for (int i = 0; i < 2; ++i) {
            const int rb = wv * 16 + i * 8;
            const int r  = rb + srow;
            gload_lds16(BT + (size_t)(n0 + r) * K + k0 + ((sslot ^ (r & 7)) << 3),
                        &Bs[rb * 64]);
        }
        __syncthreads();

        #pragma unroll
        for (int kk = 0; kk < 2; ++kk) {
            const int t = kk * 4 + (lane >> 4);
            short8 af[4], bfr[2];
            #pragma unroll
            for (int mi = 0; mi < 4; ++mi) {
                const int m = wm * 64 + mi * 16 + (lane & 15);
                af[mi] = *reinterpret_cast<const short8*>(&As[m * 64 + ((t ^ (m & 7)) << 3)]);
            }
            #pragma unroll
            for (int ni = 0; ni < 2; ++ni) {
                const int n = wn * 32 + ni * 16 + (lane & 15);
                bfr[ni] = *reinterpret_cast<const short8*>(&Bs[n * 64 + ((t ^ (n & 7)) << 3)]);
            }
            #pragma unroll
            for (int mi = 0; mi < 4; ++mi)
                #pragma unroll
                for (int ni = 0; ni < 2; ++ni)
                    acc[mi][ni] = MFMA16(af[mi], bfr[ni], acc[mi][ni]);
        }
        __syncthreads();
    }

    const int colb = n0 + wn * 32 + (lane & 15);
    const int rowb = m0 + wm * 64 + (lane >> 4) * 4;
    #pragma unroll
    for (int mi = 0; mi < 4; ++mi) {
        #pragma unroll
        for (int ni = 0; ni < 2; ++ni) {
            const int c = colb + ni * 16;
            #pragma unroll
            for (int j = 0; j < 4; ++j) {
                const int row = rowb + mi * 16 + j;
                const size_t off = (size_t)row * N + c;
                outB[off] = __float2bfloat16(acc[mi][ni][j] +
                                             bf2f(*(const short*)&residB[off]));
            }
        }
    }
}

// ---------------------------------------------------------------------------
// FUSED MLP (G4+G5), 32-row tiles: final = ob + silu(ob@Wm1+bm1)@Wm2 + bm2.
// LDS: obs 12KB + hs 32x776 (48.5KB) = 60.5KB -> 2 blocks/CU (8 waves/CU).
// Weights pre-laid FRAGMENT-ORDER (Wm1F 48frag x 6ks, Wm2F 12frag x 24ks):
// each B-frag load = contiguous 1KB wave-line from L2 (global_load_dwordx4).
// hs stride 776 elems -> all LDS traffic <=2-way (free). No h round-trip.
// Best-measured configuration (R16: total 117.1 us).
// ---------------------------------------------------------------------------
#define HSTR 776
__launch_bounds__(256, 2)
__global__ void fused_mlp32(const bf16* __restrict__ ob, const bf16* __restrict__ Wm1F,
                            const bf16* __restrict__ Wm2F, const float* __restrict__ bm1,
                            const float* __restrict__ bm2, float* __restrict__ out)
{
    __shared__ bf16 obs[32 * 192];     // 12 KB
    __shared__ bf16 hs[32 * HSTR];     // 48.5 KB

    const int m0   = blockIdx.x * 32;
    const int tid  = threadIdx.x;
    const int lane = tid & 63;
    const int wv   = tid >> 6;
    const int l15  = lane & 15;
    const int l4   = lane >> 4;

    // stage obs (768 16B chunks; k192 slot swizzle p^(row&7))
    #pragma unroll
    for (int i = 0; i < 3; ++i) {
        const int ci   = wv * 3 + i;
        const int c    = ci * 64 + lane;
        const int row  = c / 24;
        const int slot = c - row * 24;
        gload_lds16(ob + (size_t)(m0 + row) * 192 + ((slot ^ (row & 7)) << 3),
                    &obs[ci * 512]);
    }
    __syncthreads();

    // ---- phase 1: h[32x768] per wave 192 cols, 3 groups of 4 n-frags ----
    #pragma unroll
    for (int g = 0; g < 3; ++g) {
        f32x4 hacc[2][4] = {};
        #pragma unroll
        for (int ks = 0; ks < 6; ++ks) {
            short8 af[2];
            #pragma unroll
            for (int mi = 0; mi < 2; ++mi) {
                const int r = mi * 16 + l15;
                af[mi] = *reinterpret_cast<const short8*>(
                    &obs[r * 192 + (((ks * 4 + l4) ^ (r & 7)) << 3)]);
            }
            #pragma unroll
            for (int ni = 0; ni < 4; ++ni) {
                const int f = wv * 12 + g * 4 + ni;     // global n-frag 0..47
                const short8 b = *reinterpret_cast<const short8*>(
                    Wm1F + ((size_t)(f * 6 + ks) * 64 + lane) * 8);
                #pragma unroll
                for (int mi = 0; mi < 2; ++mi)
                    hacc[mi][ni] = MFMA16(af[mi], b, hacc[mi][ni]);
            }
        }
        #pragma unroll
        for (int ni = 0; ni < 4; ++ni) {
            const int col = (wv * 12 + g * 4 + ni) * 16 + l15;
            const float bb = bm1[col];
            #pragma unroll
            for (int mi = 0; mi < 2; ++mi)
                #pragma unroll
                for (int j = 0; j < 4; ++j) {
                    const int r = mi * 16 + l4 * 4 + j;
                    hs[r * HSTR + col] = __float2bfloat16(silu_f(hacc[mi][ni][j] + bb));
                }
        }
    }
    __syncthreads();

    // ---- phase 2: out[32x192], K=768; wave owns 48 cols ----
    f32x4 facc[2][3] = {};
    for (int ks = 0; ks < 24; ++ks) {
        short8 ha[2];
        #pragma unroll
        for (int mi = 0; mi < 2; ++mi) {
            const int r = mi * 16 + l15;
            ha[mi] = *reinterpret_cast<const short8*>(&hs[r * HSTR + ks * 32 + l4 * 8]);
        }
        #pragma unroll
        for (int ni = 0; ni < 3; ++ni) {
            const int f = wv * 3 + ni;                  // out n-frag 0..11
            const short8 b = *reinterpret_cast<const short8*>(
                Wm2F + ((size_t)(f * 24 + ks) * 64 + lane) * 8);
            #pragma unroll
            for (int mi = 0; mi < 2; ++mi)
                facc[mi][ni] = MFMA16(ha[mi], b, facc[mi][ni]);
        }
    }

    // epilogue: + bm2 + bf16 ob residual (from obs), fp32 out
    #pragma unroll
    for (int ni = 0; ni < 3; ++ni) {
        const int col = (wv * 3 + ni) * 16 + l15;
        const float b2 = bm2[col];
        #pragma unroll
        for (int mi = 0; mi < 2; ++mi)
            #pragma unroll
            for (int j = 0; j < 4; ++j) {
                const int r  = mi * 16 + l4 * 4 + j;
                const int ch = (col >> 3) ^ (r & 7);
                const float resid = bf2f(*reinterpret_cast<const short*>(
                    &obs[r * 192 + ch * 8 + (col & 7)]));
                out[(size_t)(m0 + r) * 192 + col] = facc[mi][ni][j] + b2 + resid;
            }
    }
}

// ---------------------------------------------------------------------------
// Depthwise 3x3 conv + bias + silu, gated (dense streams).
// ---------------------------------------------------------------------------
__launch_bounds__(256)
__global__ void dwconv_gate_v6(const bf16* __restrict__ x1, const bf16* __restrict__ sz,
                               const float* __restrict__ wT, const float* __restrict__ conv_b,
                               bf16* __restrict__ y)
{
    const int bid = blockIdx.x;
    const int swz = (bid & 7) * ((int)gridDim.x >> 3) + (bid >> 3);
    const int f   = swz * 256 + threadIdx.x;
    const int m   = f / 48;
    const int cg  = f - m * 48;
    const int c0  = cg * 8;
    const int h   = (m >> 6) & 63;
    const int w   = m & 63;

    float acc[8];
    {
        const f32x4 ba = *reinterpret_cast<const f32x4*>(&conv_b[c0]);
        const f32x4 bb = *reinterpret_cast<const f32x4*>(&conv_b[c0 + 4]);
        acc[0] = ba[0]; acc[1] = ba[1]; acc[2] = ba[2]; acc[3] = ba[3];
        acc[4] = bb[0]; acc[5] = bb[1]; acc[6] = bb[2]; acc[7] = bb[3];
    }

    #pragma unroll
    for (int r = 0; r < 3; ++r) {
        const int hh = h + r - 1;
        if (hh < 0 || hh >= HDIM) continue;
        #pragma unroll
        for (int dw = 0; dw < 3; ++dw) {
            const int ww = w + dw - 1;
            if (ww < 0 || ww >= WDIM) continue;
            const int mm  = m + (r - 1) * WDIM + (dw - 1);
            const int tap = r * 3 + dw;
            const short8 t = *reinterpret_cast<const short8*>(&x1[(size_t)mm * CIDIM + c0]);
            const f32x4 wa = *reinterpret_cast<const f32x4*>(&wT[tap * CIDIM + c0]);
            const f32x4 wb = *reinterpret_cast<const f32x4*>(&wT[tap * CIDIM + c0 + 4]);
            acc[0] += bf2f(t[0]) * wa[0]; acc[1] += bf2f(t[1]) * wa[1];
            acc[2] += bf2f(t[2]) * wa[2]; acc[3] += bf2f(t[3]) * wa[3];
            acc[4] += bf2f(t[4]) * wb[0]; acc[5] += bf2f(t[5]) * wb[1];
            acc[6] += bf2f(t[6]) * wb[2]; acc[7] += bf2f(t[7]) * wb[3];
        }
    }

    const short8 g = *reinterpret_cast<const short8*>(&sz[(size_t)m * CIDIM + c0]);
    bf16 tmp[8];
    #pragma unroll
    for (int j = 0; j < 8; ++j)
        tmp[j] = __float2bfloat16(silu_f(acc[j]) * bf2f(g[j]));
    *reinterpret_cast<short8*>(&y[(size_t)m * CIDIM + c0]) =
        *reinterpret_cast<const short8*>(tmp);
}

// ---------------------------------------------------------------------------
// ALL preprocessing in ONE launch: x->bf16, WinT/WoutT transposes,
// Wm1F/Wm2F FRAGMENT-ORDER layouts, conv_w transpose.
// ---------------------------------------------------------------------------
#define SZ_WIN  (192 * 768)
#define SZ_WOUT (384 * 192)
#define SZ_WM1  (192 * 768)
#define SZ_WM2  (768 * 192)
#define SZ_CW   (CIDIM * 9)
#define XCVT    (MTOK * CDIM / 4)
#define SZ_ALL  (XCVT + SZ_WIN + SZ_WOUT + SZ_WM1 + SZ_WM2 + SZ_CW)

__launch_bounds__(256)
__global__ void prep_all(const float* __restrict__ x, const float* __restrict__ Win,
                         const float* __restrict__ Wout, const float* __restrict__ Wm1,
                         const float* __restrict__ Wm2, const float* __restrict__ convw,
                         bf16* __restrict__ xb, bf16* __restrict__ WinT,
                         bf16* __restrict__ WoutT, bf16* __restrict__ Wm1F,
                         bf16* __restrict__ Wm2F, float* __restrict__ wTc)
{
    int idx = blockIdx.x * 256 + threadIdx.x;
    if (idx < XCVT) {
        const int i = idx * 4;
        const float4 v = *reinterpret_cast<const float4*>(&x[i]);
        xb[i + 0] = __float2bfloat16(v.x);
        xb[i + 1] = __float2bfloat16(v.y);
        xb[i + 2] = __float2bfloat16(v.z);
        xb[i + 3] = __float2bfloat16(v.w);
        return;
    }
    idx -= XCVT;
    if (idx < SZ_WIN) {
        const int r = idx / 768, c = idx % 768;
        WinT[(size_t)c * 192 + r] = __float2bfloat16(Win[idx]);
        return;
    }
    idx -= SZ_WIN;
    if (idx < SZ_WOUT) {
        const int r = idx / 192, c = idx % 192;
        WoutT[(size_t)c * 384 + r] = __float2bfloat16(Wout[idx]);
        return;
    }
    idx -= SZ_WOUT;
    if (idx < SZ_WM1) {
        // fragment order: [f:48][ks:6][lane:64][e:8]; row=f*16+(l&15), k=ks*32+(l>>4)*8+e
        const int f  = idx / 3072;
        const int r1 = idx - f * 3072;
        const int ks = r1 / 512;
        const int r2 = r1 - ks * 512;
        const int l  = r2 >> 3;
        const int e  = r2 & 7;
        const int row = f * 16 + (l & 15);
        const int k   = ks * 32 + (l >> 4) * 8 + e;
        Wm1F[idx] = __float2bfloat16(Wm1[(size_t)k * 768 + row]);
        return;
    }
    idx -= SZ_WM1;
    if (idx < SZ_WM2) {
        // fragment order: [f:12][ks:24][lane:64][e:8]; row=f*16+(l&15), k=ks*32+(l>>4)*8+e
        const int f  = idx / 12288;
        const int r1 = idx - f * 12288;
        const int ks = r1 / 512;
        const int r2 = r1 - ks * 512;
        const int l  = r2 >> 3;
        const int e  = r2 & 7;
        const int row = f * 16 + (l & 15);
        const int k   = ks * 32 + (l >> 4) * 8 + e;
        Wm2F[idx] = __float2bfloat16(Wm2[(size_t)k * 192 + row]);
        return;
    }
    idx -= SZ_WM2;
    if (idx < SZ_CW) {
        const int ci = idx / 9, t = idx % 9;
        wTc[t * CIDIM + ci] = convw[idx];
    }
}

// ---------------------------------------------------------------------------
extern "C" void kernel_launch(void* const* d_in, const int* in_sizes, int n_in,
                              void* d_out, int out_size, void* d_ws, size_t ws_size,
                              hipStream_t stream)
{
    const float* x      = (const float*)d_in[0];
    const float* Win    = (const float*)d_in[1];
    const float* conv_w = (const float*)d_in[2];
    const float* conv_b = (const float*)d_in[3];
    const float* Wout   = (const float*)d_in[4];
    const float* Wm1    = (const float*)d_in[5];
    const float* bm1    = (const float*)d_in[6];
    const float* Wm2    = (const float*)d_in[7];
    const float* bm2    = (const float*)d_in[8];
    float* out = (float*)d_out;

    char* ws = (char*)d_ws;
    size_t o = 0;
    bf16*  xb    = (bf16*)(ws + o); o += (size_t)MTOK * CDIM * 2;
    bf16*  WinT  = (bf16*)(ws + o); o += (size_t)768 * 192 * 2;
    bf16*  WoutT = (bf16*)(ws + o); o += (size_t)192 * 384 * 2;
    bf16*  Wm1F  = (bf16*)(ws + o); o += (size_t)SZ_WM1 * 2;
    bf16*  Wm2F  = (bf16*)(ws + o); o += (size_t)SZ_WM2 * 2;
    float* wTc   = (float*)(ws + o); o += (size_t)9 * CIDIM * 4;
    bf16*  ws_x1 = (bf16*)(ws + o); o += (size_t)MTOK * CIDIM * 2;   // dense x1 [M,384]
    bf16*  ws_sz = (bf16*)(ws + o); o += (size_t)MTOK * CIDIM * 2;   // dense 4*silu(z)
    bf16*  ws_y  = (bf16*)(ws + o); o += (size_t)MTOK * CIDIM * 2;
    bf16*  ws_ob = (bf16*)(ws + o); o += (size_t)MTOK * CDIM * 2;    // out bf16 [M,192]

    // 0) all conversions / re-layouts in one launch
    prep_all<<<dim3((SZ_ALL + 255) / 256), dim3(256), 0, stream>>>(
        x, Win, Wout, Wm1, Wm2, conv_w, xb, WinT, WoutT, Wm1F, Wm2F, wTc);

    // 1) xz = x @ Win  [M,768], K=192 -> split dense x1 / sz(=4*silu(z))
    gemm_k192_p<0><<<dim3(12 * NSTRIPE), dim3(256), 0, stream>>>(
        xb, WinT, nullptr, ws_x1, ws_sz);

    // 2) y = silu(dwconv(x1)+b) * sz -> bf16
    dwconv_gate_v6<<<dim3(MTOK * 48 / 256), dim3(256), 0, stream>>>(
        ws_x1, ws_sz, wTc, conv_b, ws_y);

    // 3) out = xb + y @ Wout   [M,192], K=384 -> bf16 ob
    gemm_g3<<<dim3(3 * 256), dim3(256), 0, stream>>>(
        ws_y, WoutT, xb, ws_ob, MTOK, CDIM, CIDIM, 3);

    // 4+5) final = ob + silu(ob@Wm1+bm1)@Wm2 + bm2 -> fp32 out (FUSED, 32-row)
    fused_mlp32<<<dim3(MTOK / 32), dim3(256), 0, stream>>>(
        ws_ob, Wm1F, Wm2F, bm1, bm2, out);
}